// Round 3
// baseline (468.202 us; speedup 1.0000x reference)
//
#include <hip/hip_runtime.h>
#include <hip/hip_bf16.h>

#define B_    8
#define T_    8192
#define CHUNK 64          // timesteps per block
#define NCPB  128         // chunks (blocks) per batch
#define GRID  (B_ * NCPB) // 1024 = exactly 4 blocks/CU * 256 CUs -> co-resident
#define WSTEP 16          // timesteps per wave
#define GP    136         // LDS pitch (ushorts) for W hi/lo (16B-aligned rows, 2-way bank alias = free)
#define MP    72          // sigma-path LDS pitch

typedef float  floatx4  __attribute__((ext_vector_type(4)));
typedef __bf16 bf16x8   __attribute__((ext_vector_type(8)));
typedef unsigned short ushortx8 __attribute__((ext_vector_type(8)));

__device__ inline unsigned short f2bf(float f) {
  unsigned u = __float_as_uint(f);
  u = u + 0x7FFFu + ((u >> 16) & 1u);   // RNE to bf16
  return (unsigned short)(u >> 16);
}
__device__ inline float bf2f(unsigned short h) {
  return __uint_as_float(((unsigned)h) << 16);
}

#define AL(p)    __hip_atomic_load((p), __ATOMIC_ACQUIRE, __HIP_MEMORY_SCOPE_AGENT)
#define RLL(p)   __hip_atomic_load((p), __ATOMIC_RELAXED, __HIP_MEMORY_SCOPE_AGENT)
#define RSS(p,v) __hip_atomic_store((p), (v), __ATOMIC_RELAXED, __HIP_MEMORY_SCOPE_AGENT)
#define RELS(p,v) __hip_atomic_store((p), (v), __ATOMIC_RELEASE, __HIP_MEMORY_SCOPE_AGENT)

// per-step coefficient math (|theta| < 1e-3 so 2-term poly is fp32-exact)
#define STEP_PREP()                                                     \
    float alpha = alpha0 * __expf(a_ + tmv);                            \
    float omega = omega0 * __expf(o_ + tmv);                            \
    float rho = __expf(-alpha * dtv);                                   \
    float th  = omega * dtv;                                            \
    float th2 = th * th;                                                \
    float st  = th * fmaf(th2, -0.16666667f, 1.f);                      \
    float ct  = fmaf(th2, -0.5f, 1.f);                                  \
    float ar  = rho * ct, ai = rho * st;

__global__ __launch_bounds__(256, 4) void k_fused(
    const float* __restrict__ x,  const float* __restrict__ dtp,
    const float* __restrict__ am, const float* __restrict__ om,
    const float* __restrict__ tm, const float* __restrict__ sr,
    const float* __restrict__ si, const float* __restrict__ traw,
    const float* __restrict__ bb, const float* __restrict__ W,
    float* __restrict__ out, int* __restrict__ flags,
    float* __restrict__ AGG, float* __restrict__ INC,
    float* __restrict__ sigv) {
  __shared__ __align__(16) unsigned char smem[34816];

  const int tid  = threadIdx.x;
  const int lane = tid & 63;
  const int wv   = tid >> 6;
  const int l15  = lane & 15;
  const int q    = lane >> 4;
  const int g    = blockIdx.x;
  const int b    = g >> 7;
  const int c    = g & (NCPB - 1);

  // ================= sigma (block 0 only; publishes behind flag) =========
  if (g == 0) {
    unsigned short* Ma = (unsigned short*)smem;
    unsigned short* Mb = Ma + 64 * MP;
    float* red = (float*)(smem + 18432);
    float* vsh = red + 4;
    int*   jsh = (int*)(vsh + 64);

    floatx4 acc[4] = {};
    const int arow = 16 * wv + l15;
    for (int s = 0; s < 4; ++s) {
      const int kb = 32 * s + 8 * q;
      float4 a0 = *(const float4*)(W + arow * 128 + kb);
      float4 a1 = *(const float4*)(W + arow * 128 + kb + 4);
      ushortx8 ua;
      ua[0] = f2bf(a0.x); ua[1] = f2bf(a0.y); ua[2] = f2bf(a0.z); ua[3] = f2bf(a0.w);
      ua[4] = f2bf(a1.x); ua[5] = f2bf(a1.y); ua[6] = f2bf(a1.z); ua[7] = f2bf(a1.w);
      bf16x8 av = __builtin_bit_cast(bf16x8, ua);
      for (int tn = 0; tn < 4; ++tn) {
        const int brow = 16 * tn + l15;
        float4 b0 = *(const float4*)(W + brow * 128 + kb);
        float4 b1 = *(const float4*)(W + brow * 128 + kb + 4);
        ushortx8 ub;
        ub[0] = f2bf(b0.x); ub[1] = f2bf(b0.y); ub[2] = f2bf(b0.z); ub[3] = f2bf(b0.w);
        ub[4] = f2bf(b1.x); ub[5] = f2bf(b1.y); ub[6] = f2bf(b1.z); ub[7] = f2bf(b1.w);
        bf16x8 bv = __builtin_bit_cast(bf16x8, ub);
        acc[tn] = __builtin_amdgcn_mfma_f32_16x16x32_bf16(av, bv, acc[tn], 0, 0, 0);
      }
    }
    float mx = 0.f;
    for (int tn = 0; tn < 4; ++tn)
      for (int r = 0; r < 4; ++r) mx = fmaxf(mx, fabsf(acc[tn][r]));
    for (int off = 32; off; off >>= 1) mx = fmaxf(mx, __shfl_xor(mx, off));
    if (lane == 0) red[wv] = mx;
    __syncthreads();
    {
      float gm  = fmaxf(fmaxf(red[0], red[1]), fmaxf(red[2], red[3]));
      float inv = 1.f / gm;
      for (int tn = 0; tn < 4; ++tn)
        for (int r = 0; r < 4; ++r)
          Ma[(16 * wv + 4 * q + r) * MP + 16 * tn + l15] = f2bf(acc[tn][r] * inv);
    }
    __syncthreads();

    unsigned short* srcm = Ma;
    unsigned short* dstm = Mb;
    for (int it = 0; it < 8; ++it) {
      floatx4 f[4] = {};
      for (int s = 0; s < 2; ++s) {
        const int kb = 32 * s + 8 * q;
        uint4 ua4 = *(const uint4*)(srcm + (16 * wv + l15) * MP + kb);
        bf16x8 av = __builtin_bit_cast(bf16x8, ua4);
        for (int tn = 0; tn < 4; ++tn) {
          const int n = 16 * tn + l15;
          ushortx8 ub;
          #pragma unroll
          for (int j = 0; j < 8; ++j) ub[j] = srcm[(kb + j) * MP + n];
          bf16x8 bv = __builtin_bit_cast(bf16x8, ub);
          f[tn] = __builtin_amdgcn_mfma_f32_16x16x32_bf16(av, bv, f[tn], 0, 0, 0);
        }
      }
      float m2 = 0.f;
      for (int tn = 0; tn < 4; ++tn)
        for (int r = 0; r < 4; ++r) m2 = fmaxf(m2, fabsf(f[tn][r]));
      for (int off = 32; off; off >>= 1) m2 = fmaxf(m2, __shfl_xor(m2, off));
      if (lane == 0) red[wv] = m2;
      __syncthreads();
      {
        float gm2  = fmaxf(fmaxf(red[0], red[1]), fmaxf(red[2], red[3]));
        float inv2 = 1.f / gm2;
        for (int tn = 0; tn < 4; ++tn)
          for (int r = 0; r < 4; ++r)
            dstm[(16 * wv + 4 * q + r) * MP + 16 * tn + l15] = f2bf(f[tn][r] * inv2);
      }
      __syncthreads();
      unsigned short* t2 = srcm; srcm = dstm; dstm = t2;
    }

    if (tid == 0) {
      int jb = 0; float best = -1.f;
      for (int j = 0; j < 64; ++j) {
        float dv = bf2f(srcm[j * MP + j]);
        if (dv > best) { best = dv; jb = j; }
      }
      *jsh = jb;
    }
    __syncthreads();
    if (tid < 64) vsh[tid] = bf2f(srcm[tid * MP + *jsh]);
    __syncthreads();

    if (wv == 0) {
      float wa = 0.f, wb = 0.f;
      for (int i = 0; i < 64; ++i) {
        float vi = vsh[i];
        wa = fmaf(W[i * 128 + lane], vi, wa);
        wb = fmaf(W[i * 128 + 64 + lane], vi, wb);
      }
      float num = wa * wa + wb * wb;
      float den = vsh[lane] * vsh[lane];
      for (int off = 32; off; off >>= 1) {
        num += __shfl_xor(num, off);
        den += __shfl_xor(den, off);
      }
      if (lane == 0) {
        RSS(sigv, 1.f / sqrtf(num / den));
        RELS(&flags[GRID], 1);
      }
    }
    __syncthreads();   // R1 dead; fall through to normal chunk work
  }

  // ================= chunk pipeline (all blocks) ==========================
  const int bt0w = b * T_ + c * CHUNK + wv * WSTEP;  // this wave's first (b,t)

  // ---- stage W -> bf16 hi/lo in LDS
  unsigned short* Wh = (unsigned short*)smem;
  unsigned short* Wl = Wh + 64 * GP;
  #pragma unroll
  for (int j = 0; j < 8; ++j) {
    const int v4 = tid + 256 * j;
    float4 w4 = ((const float4*)W)[v4];
    const int e = v4 * 4;
    const int row = e >> 7, col = e & 127;
    float a4[4] = {w4.x, w4.y, w4.z, w4.w};
    unsigned short h[4], l[4];
    #pragma unroll
    for (int i = 0; i < 4; ++i) {
      h[i] = f2bf(a4[i]);
      l[i] = f2bf(a4[i] - bf2f(h[i]));
    }
    *(uint2*)(Wh + row * GP + col) =
        make_uint2((unsigned)h[0] | ((unsigned)h[1] << 16), (unsigned)h[2] | ((unsigned)h[3] << 16));
    *(uint2*)(Wl + row * GP + col) =
        make_uint2((unsigned)l[0] | ((unsigned)l[1] << 16), (unsigned)l[2] | ((unsigned)l[3] << 16));
  }
  __syncthreads();

  // ---- u = x*W^T for this wave's 16 steps (hi/lo MFMA)
  floatx4 acc[4] = {};
  #pragma unroll
  for (int s = 0; s < 4; ++s) {
    const float* xp = x + ((size_t)(bt0w + l15) << 7) + 32 * s + 8 * q;
    float4 x0 = *(const float4*)xp;
    float4 x1 = *(const float4*)(xp + 4);
    float xs8[8] = {x0.x, x0.y, x0.z, x0.w, x1.x, x1.y, x1.z, x1.w};
    ushortx8 uh, ul;
    #pragma unroll
    for (int j = 0; j < 8; ++j) {
      unsigned short h = f2bf(xs8[j]);
      uh[j] = h;
      ul[j] = f2bf(xs8[j] - bf2f(h));
    }
    bf16x8 ah = __builtin_bit_cast(bf16x8, uh);
    bf16x8 al = __builtin_bit_cast(bf16x8, ul);
    #pragma unroll
    for (int t = 0; t < 4; ++t) {
      bf16x8 bh = __builtin_bit_cast(bf16x8, *(const uint4*)(Wh + (16 * t + l15) * GP + 32 * s + 8 * q));
      bf16x8 bl = __builtin_bit_cast(bf16x8, *(const uint4*)(Wl + (16 * t + l15) * GP + 32 * s + 8 * q));
      acc[t] = __builtin_amdgcn_mfma_f32_16x16x32_bf16(ah, bh, acc[t], 0, 0, 0);
      acc[t] = __builtin_amdgcn_mfma_f32_16x16x32_bf16(al, bh, acc[t], 0, 0, 0);
      acc[t] = __builtin_amdgcn_mfma_f32_16x16x32_bf16(ah, bl, acc[t], 0, 0, 0);
    }
  }
  __syncthreads();   // everyone done reading W LDS

  // ---- transpose u (C layout: t=4q+r, k=16n+l15) -> per-lane column k=lane
  float* tb = (float*)(smem + (wv << 12));
  #pragma unroll
  for (int t = 0; t < 4; ++t)
    #pragma unroll
    for (int r = 0; r < 4; ++r)
      tb[(4 * q + r) * 64 + 16 * t + l15] = acc[t][r];
  __syncthreads();
  float v[WSTEP];
  #pragma unroll
  for (int i = 0; i < WSTEP; ++i) v[i] = tb[i * 64 + lane];

  // ---- per-step coefficients + wave-local transform (A, UP, UQ)
  const float tau    = log1pf(__expf(traw[0])) + 1e-3f;
  const float alpha0 = (log1pf(__expf(sr[lane])) + 1e-6f) * tau;
  const float omega0 = si[lane] * tau;
  const float bk     = bb[lane];

  float sar[WSTEP], sai[WSTEP];
  float Ar = 1.f, Ai = 0.f, UPr = 0.f, UPi = 0.f, UQr = 0.f, UQi = 0.f;
  {
    size_t base = (size_t)bt0w * 64 + lane;
    #pragma unroll 4
    for (int i = 0; i < WSTEP; ++i) {
      float a_  = am[base];
      float o_  = om[base];
      float tmv = tm[bt0w + i];
      float dtv = dtp[bt0w + i];
      STEP_PREP();
      sar[i] = ar; sai[i] = ai;
      float nPr = fmaf(ar, UPr, fmaf(-ai, UPi, v[i]));
      float nPi = fmaf(ar, UPi, ai * UPr);
      UPr = nPr; UPi = nPi;
      float nQr = fmaf(ar, UQr, fmaf(-ai, UQi, bk));
      float nQi = fmaf(ar, UQi, ai * UQr);
      UQr = nQr; UQi = nQi;
      float nAr = fmaf(ar, Ar, -ai * Ai);
      float nAi = fmaf(ar, Ai, ai * Ar);
      Ar = nAr; Ai = nAi;
      base += 64;
    }
  }

  // ---- publish wave transforms, compose block aggregate + my wave prefix
  float* pub = (float*)(smem + 16384);
  pub[(wv * 6 + 0) * 64 + lane] = Ar;
  pub[(wv * 6 + 1) * 64 + lane] = Ai;
  pub[(wv * 6 + 2) * 64 + lane] = UPr;
  pub[(wv * 6 + 3) * 64 + lane] = UPi;
  pub[(wv * 6 + 4) * 64 + lane] = UQr;
  pub[(wv * 6 + 5) * 64 + lane] = UQi;
  __syncthreads();

  float cAr = 1.f, cAi = 0.f, cPr = 0.f, cPi = 0.f, cQr = 0.f, cQi = 0.f;
  float pAr = 1.f, pAi = 0.f, pPr = 0.f, pPi = 0.f, pQr = 0.f, pQi = 0.f;
  #pragma unroll
  for (int w2 = 0; w2 < 4; ++w2) {
    if (w2 == wv) { pAr = cAr; pAi = cAi; pPr = cPr; pPi = cPi; pQr = cQr; pQi = cQi; }
    float tAr = pub[(w2 * 6 + 0) * 64 + lane], tAi = pub[(w2 * 6 + 1) * 64 + lane];
    float tPr = pub[(w2 * 6 + 2) * 64 + lane], tPi = pub[(w2 * 6 + 3) * 64 + lane];
    float tQr = pub[(w2 * 6 + 4) * 64 + lane], tQi = pub[(w2 * 6 + 5) * 64 + lane];
    float nAr = tAr * cAr - tAi * cAi;
    float nAi = tAr * cAi + tAi * cAr;
    float nPr = fmaf(tAr, cPr, fmaf(-tAi, cPi, tPr));
    float nPi = fmaf(tAr, cPi, fmaf( tAi, cPr, tPi));
    float nQr = fmaf(tAr, cQr, fmaf(-tAi, cQi, tQr));
    float nQi = fmaf(tAr, cQi, fmaf( tAi, cQr, tQi));
    cAr = nAr; cAi = nAi; cPr = nPr; cPi = nPi; cQr = nQr; cQi = nQi;
  }

  // ---- wave 0: publish aggregate, lookback, publish inclusive, share z_in
  float* zsh = (float*)(smem + 22528);
  if (wv == 0) {
    {
      float* ag = AGG + (size_t)g * 384 + lane;
      RSS(ag + 0 * 64, cAr); RSS(ag + 1 * 64, cAi);
      RSS(ag + 2 * 64, cPr); RSS(ag + 3 * 64, cPi);
      RSS(ag + 4 * 64, cQr); RSS(ag + 5 * 64, cQi);
      __threadfence();
      if (lane == 0) RELS(&flags[g], 1);
    }

    float zPr = 0.f, zPi = 0.f, zQr = 0.f, zQi = 0.f;
    if (c != 0) {
      float aAr = 1.f, aAi = 0.f, aPr = 0.f, aPi = 0.f, aQr = 0.f, aQi = 0.f;
      const int gbase = b << 7;
      int j = g - 1;
      bool done = false;
      while (!done) {
        int jlo = (j - 3 < gbase) ? gbase : j - 3;
        int cnt = j - jlo + 1;
        int fl[4];
        bool rdy;
        do {
          rdy = true;
          for (int u2 = 0; u2 < cnt; ++u2) fl[u2] = AL(&flags[j - u2]);
          for (int u2 = 0; u2 < cnt; ++u2) rdy = rdy && (fl[u2] == 1 || fl[u2] == 2);
          if (!rdy) __builtin_amdgcn_s_sleep(1);
        } while (!rdy);
        int stop = cnt;
        for (int u2 = 0; u2 < cnt; ++u2) { if (fl[u2] == 2) { stop = u2; break; } }
        float dA[4][6];
        for (int u2 = 0; u2 < stop; ++u2) {
          const float* ag = AGG + (size_t)(j - u2) * 384 + lane;
          for (int m = 0; m < 6; ++m) dA[u2][m] = RLL(ag + m * 64);
        }
        float zi4[4];
        if (stop < cnt) {
          const float* ic = INC + (size_t)(j - stop) * 256 + lane;
          for (int m = 0; m < 4; ++m) zi4[m] = RLL(ic + m * 64);
        }
        for (int u2 = 0; u2 < stop; ++u2) {
          float tAr = dA[u2][0], tAi = dA[u2][1];
          float tPr = dA[u2][2], tPi = dA[u2][3];
          float tQr = dA[u2][4], tQi = dA[u2][5];
          aPr += aAr * tPr - aAi * tPi;
          aPi += aAr * tPi + aAi * tPr;
          aQr += aAr * tQr - aAi * tQi;
          aQi += aAr * tQi + aAi * tQr;
          float nAr = aAr * tAr - aAi * tAi;
          float nAi = aAr * tAi + aAi * tAr;
          aAr = nAr; aAi = nAi;
        }
        if (stop < cnt) {
          zPr = aPr + aAr * zi4[0] - aAi * zi4[1];
          zPi = aPi + aAr * zi4[1] + aAi * zi4[0];
          zQr = aQr + aAr * zi4[2] - aAi * zi4[3];
          zQi = aQi + aAr * zi4[3] + aAi * zi4[2];
          done = true;
        } else {
          j -= cnt;
          if (j < gbase) { zPr = aPr; zPi = aPi; zQr = aQr; zQi = aQi; done = true; }
        }
      }
    }

    // inclusive of this block
    {
      float ZPr = fmaf(cAr, zPr, fmaf(-cAi, zPi, cPr));
      float ZPi = fmaf(cAr, zPi, fmaf( cAi, zPr, cPi));
      float ZQr = fmaf(cAr, zQr, fmaf(-cAi, zQi, cQr));
      float ZQi = fmaf(cAr, zQi, fmaf( cAi, zQr, cQi));
      float* ic = INC + (size_t)g * 256 + lane;
      RSS(ic + 0 * 64, ZPr); RSS(ic + 1 * 64, ZPi);
      RSS(ic + 2 * 64, ZQr); RSS(ic + 3 * 64, ZQi);
      __threadfence();
      if (lane == 0) RELS(&flags[g], 2);
    }
    zsh[lane] = zPr; zsh[64 + lane] = zPi; zsh[128 + lane] = zQr; zsh[192 + lane] = zQi;
  }
  __syncthreads();

  // ---- apply wave prefix to block-incoming state
  float zinPr = zsh[lane], zinPi = zsh[64 + lane];
  float zinQr = zsh[128 + lane], zinQi = zsh[192 + lane];
  float zPr = fmaf(pAr, zinPr, fmaf(-pAi, zinPi, pPr));
  float zPi = fmaf(pAr, zinPi, fmaf( pAi, zinPr, pPi));
  float zQr = fmaf(pAr, zinQr, fmaf(-pAi, zinQi, pQr));
  float zQi = fmaf(pAr, zinQi, fmaf( pAi, zinQr, pQi));

  // ---- sigma poll (published by block 0 early)
  int sf;
  do { sf = AL(&flags[GRID]); if (sf != 1) __builtin_amdgcn_s_sleep(1); } while (sf != 1);
  const float invs = RLL(sigv);

  // ---- replay from registers and write out [C | S]
  float* op = out + ((size_t)bt0w << 7) + lane;
  #pragma unroll 4
  for (int i = 0; i < WSTEP; ++i) {
    float ar = sar[i], ai = sai[i];
    float nPr = fmaf(ar, zPr, fmaf(-ai, zPi, v[i]));
    float nPi = fmaf(ar, zPi, ai * zPr);
    zPr = nPr; zPi = nPi;
    float nQr = fmaf(ar, zQr, fmaf(-ai, zQi, bk));
    float nQi = fmaf(ar, zQi, ai * zQr);
    zQr = nQr; zQi = nQi;
    op[0]  = fmaf(invs, zPr, zQr);   // C
    op[64] = fmaf(invs, zPi, zQi);   // S
    op += 128;
  }
}

// ---------------------------------------------------------------------------
extern "C" void kernel_launch(void* const* d_in, const int* in_sizes, int n_in,
                              void* d_out, int out_size, void* d_ws, size_t ws_size,
                              hipStream_t stream) {
  (void)in_sizes; (void)n_in; (void)out_size; (void)ws_size;
  const float* x    = (const float*)d_in[0];
  const float* dtp  = (const float*)d_in[1];
  const float* amod = (const float*)d_in[2];
  const float* omod = (const float*)d_in[3];
  const float* tmod = (const float*)d_in[4];
  const float* srr  = (const float*)d_in[5];
  const float* sim  = (const float*)d_in[6];
  const float* traw = (const float*)d_in[7];
  const float* W    = (const float*)d_in[8];
  const float* bb   = (const float*)d_in[9];
  float* out = (float*)d_out;

  int*   flags = (int*)d_ws;                 // [0..1023] block flags, [1024] sigma flag
  float* fws   = (float*)d_ws;
  float* sigv  = fws + 1025;
  float* AGG   = fws + 2048;                 // [1024][6][64]
  float* INC   = AGG + (size_t)GRID * 384;   // [1024][4][64]

  k_fused<<<GRID, 256, 0, stream>>>(x, dtp, amod, omod, tmod, srr, sim, traw,
                                    bb, W, out, flags, AGG, INC, sigv);
}

// Round 5
// 420.235 us; speedup vs baseline: 1.1141x; 1.1141x over previous
//
#include <hip/hip_runtime.h>
#include <hip/hip_bf16.h>

#define B_    8
#define T_    8192
#define CHUNK 128         // timesteps per block
#define NCPB  64          // chunks per batch
#define GRID  512         // 2 blocks/CU * 256 CU -> co-resident by construction
#define WSTEP 32          // timesteps per wave
#define TBP   65          // transpose LDS pitch (floats)
#define MP    72          // sigma LDS pitch (ushorts); 144B rows = 16B-aligned

typedef float  floatx4  __attribute__((ext_vector_type(4)));
typedef __bf16 bf16x8   __attribute__((ext_vector_type(8)));
typedef unsigned short ushortx8 __attribute__((ext_vector_type(8)));

__device__ inline unsigned short f2bf(float f) {
  unsigned u = __float_as_uint(f);
  u = u + 0x7FFFu + ((u >> 16) & 1u);   // RNE to bf16
  return (unsigned short)(u >> 16);
}
__device__ inline float bf2f(unsigned short h) {
  return __uint_as_float(((unsigned)h) << 16);
}

#define RLL(p)   __hip_atomic_load((p), __ATOMIC_RELAXED, __HIP_MEMORY_SCOPE_AGENT)
#define RSS(p,v) __hip_atomic_store((p), (v), __ATOMIC_RELAXED, __HIP_MEMORY_SCOPE_AGENT)

// manual grid barrier: counter zeroed by hipMemsetAsync before each launch.
// Safe because grid (512) == guaranteed co-residency capacity:
// __launch_bounds__(256,2) caps VGPR at 256 (>=2 waves/SIMD -> 2 blocks/CU),
// LDS 23.5KB -> 2 blocks/CU even under a 64KiB/CU assumption.
__device__ inline void gbar(int* ctr) {
  __threadfence();
  __syncthreads();
  if (threadIdx.x == 0) {
    __hip_atomic_fetch_add(ctr, 1, __ATOMIC_ACQ_REL, __HIP_MEMORY_SCOPE_AGENT);
    while (__hip_atomic_load(ctr, __ATOMIC_ACQUIRE, __HIP_MEMORY_SCOPE_AGENT) < GRID)
      __builtin_amdgcn_s_sleep(1);
  }
  __syncthreads();
  __threadfence();
}

// per-step coefficient math (|theta| < 1e-3 so 2-term poly is fp32-exact)
#define STEP_PREP()                                                     \
    float alpha = alpha0 * __expf(a_ + tmv);                            \
    float omega = omega0 * __expf(o_ + tmv);                            \
    float rho = __expf(-alpha * dtv);                                   \
    float th  = omega * dtv;                                            \
    float th2 = th * th;                                                \
    float st  = th * fmaf(th2, -0.16666667f, 1.f);                      \
    float ct  = fmaf(th2, -0.5f, 1.f);                                  \
    float ar  = rho * ct, ai = rho * st;

struct Params {
  const float *x, *dtp, *am, *om, *tm, *sr, *si, *traw, *bb, *W;
  float *out, *AGG, *Z0, *sigv;
  int *bar;
};

__global__ __launch_bounds__(256, 2) void k_fused(Params p) {
  __shared__ __align__(16) unsigned char smem[23552];

  const int tid  = threadIdx.x;
  const int lane = tid & 63;
  const int wv   = tid >> 6;
  const int wvu  = __builtin_amdgcn_readfirstlane(wv);
  const int l15  = lane & 15;
  const int q    = lane >> 4;
  const int g    = blockIdx.x;
  const int b    = g >> 6;
  const int c    = g & (NCPB - 1);

  // ================= phase A: u = x*W^T via hi/lo bf16 MFMA ===============
  // wave handles 32 timesteps (2 m-tiles of 16); W fragments direct from
  // global (W is 32KB, L1-resident after first touch).
  const int bt0w = b * T_ + c * CHUNK + wvu * WSTEP;

  floatx4 acc[2][4] = {};
  #pragma unroll
  for (int s = 0; s < 4; ++s) {
    bf16x8 ah[2], al[2];
    #pragma unroll
    for (int mt = 0; mt < 2; ++mt) {
      const float* xp = p.x + ((size_t)(bt0w + 16 * mt + l15) << 7) + 32 * s + 8 * q;
      float4 x0 = *(const float4*)xp;
      float4 x1 = *(const float4*)(xp + 4);
      float xs8[8] = {x0.x, x0.y, x0.z, x0.w, x1.x, x1.y, x1.z, x1.w};
      ushortx8 uh, ul;
      #pragma unroll
      for (int j = 0; j < 8; ++j) {
        unsigned short h = f2bf(xs8[j]);
        uh[j] = h;
        ul[j] = f2bf(xs8[j] - bf2f(h));
      }
      ah[mt] = __builtin_bit_cast(bf16x8, uh);
      al[mt] = __builtin_bit_cast(bf16x8, ul);
    }
    #pragma unroll
    for (int nt = 0; nt < 4; ++nt) {
      const float* wp = p.W + (16 * nt + l15) * 128 + 32 * s + 8 * q;
      float4 w0 = *(const float4*)wp;
      float4 w1 = *(const float4*)(wp + 4);
      float ws8[8] = {w0.x, w0.y, w0.z, w0.w, w1.x, w1.y, w1.z, w1.w};
      ushortx8 vh, vl;
      #pragma unroll
      for (int j = 0; j < 8; ++j) {
        unsigned short h = f2bf(ws8[j]);
        vh[j] = h;
        vl[j] = f2bf(ws8[j] - bf2f(h));
      }
      bf16x8 bh = __builtin_bit_cast(bf16x8, vh);
      bf16x8 bl = __builtin_bit_cast(bf16x8, vl);
      #pragma unroll
      for (int mt = 0; mt < 2; ++mt) {
        acc[mt][nt] = __builtin_amdgcn_mfma_f32_16x16x32_bf16(ah[mt], bh, acc[mt][nt], 0, 0, 0);
        acc[mt][nt] = __builtin_amdgcn_mfma_f32_16x16x32_bf16(al[mt], bh, acc[mt][nt], 0, 0, 0);
        acc[mt][nt] = __builtin_amdgcn_mfma_f32_16x16x32_bf16(ah[mt], bl, acc[mt][nt], 0, 0, 0);
      }
    }
  }

  // ---- transpose u per m-tile (wave-local LDS; in-wave DS ops are in-order)
  float v[WSTEP];
  {
    float* tb = (float*)smem + wvu * 1088;   // 4352 B per wave
    #pragma unroll
    for (int mt = 0; mt < 2; ++mt) {
      #pragma unroll
      for (int nt = 0; nt < 4; ++nt)
        #pragma unroll
        for (int r = 0; r < 4; ++r)
          tb[(4 * q + r) * TBP + 16 * nt + l15] = acc[mt][nt][r];
      #pragma unroll
      for (int i = 0; i < 16; ++i) v[16 * mt + i] = tb[i * TBP + lane];
    }
  }

  // ---- per-step coefficients + wave-local transform (A, UP, UQ)
  const float tau    = log1pf(__expf(p.traw[0])) + 1e-3f;
  const float alpha0 = (log1pf(__expf(p.sr[lane])) + 1e-6f) * tau;
  const float omega0 = p.si[lane] * tau;
  const float bk     = p.bb[lane];

  float sar[WSTEP], sai[WSTEP];
  float Ar = 1.f, Ai = 0.f, UPr = 0.f, UPi = 0.f, UQr = 0.f, UQi = 0.f;
  {
    const size_t base0 = (size_t)bt0w * 64 + lane;
    #pragma unroll
    for (int i = 0; i < WSTEP; ++i) {
      float a_  = p.am[base0 + 64 * i];
      float o_  = p.om[base0 + 64 * i];
      float tmv = p.tm[bt0w + i];
      float dtv = p.dtp[bt0w + i];
      STEP_PREP();
      sar[i] = ar; sai[i] = ai;
      float nPr = fmaf(ar, UPr, fmaf(-ai, UPi, v[i]));
      float nPi = fmaf(ar, UPi, ai * UPr);
      UPr = nPr; UPi = nPi;
      float nQr = fmaf(ar, UQr, fmaf(-ai, UQi, bk));
      float nQi = fmaf(ar, UQi, ai * UQr);
      UQr = nQr; UQi = nQi;
      float nAr = fmaf(ar, Ar, -ai * Ai);
      float nAi = fmaf(ar, Ai, ai * Ar);
      Ar = nAr; Ai = nAi;
    }
  }

  // ---- publish wave transforms, compose block aggregate + my wave prefix
  float* pub = (float*)(smem + 17408);
  pub[(wv * 6 + 0) * 64 + lane] = Ar;
  pub[(wv * 6 + 1) * 64 + lane] = Ai;
  pub[(wv * 6 + 2) * 64 + lane] = UPr;
  pub[(wv * 6 + 3) * 64 + lane] = UPi;
  pub[(wv * 6 + 4) * 64 + lane] = UQr;
  pub[(wv * 6 + 5) * 64 + lane] = UQi;
  __syncthreads();

  float cAr = 1.f, cAi = 0.f, cPr = 0.f, cPi = 0.f, cQr = 0.f, cQi = 0.f;
  float pAr = 1.f, pAi = 0.f, pPr = 0.f, pPi = 0.f, pQr = 0.f, pQi = 0.f;
  #pragma unroll
  for (int w2 = 0; w2 < 4; ++w2) {
    if (w2 == wv) { pAr = cAr; pAi = cAi; pPr = cPr; pPi = cPi; pQr = cQr; pQi = cQi; }
    float tAr = pub[(w2 * 6 + 0) * 64 + lane], tAi = pub[(w2 * 6 + 1) * 64 + lane];
    float tPr = pub[(w2 * 6 + 2) * 64 + lane], tPi = pub[(w2 * 6 + 3) * 64 + lane];
    float tQr = pub[(w2 * 6 + 4) * 64 + lane], tQi = pub[(w2 * 6 + 5) * 64 + lane];
    float nAr = tAr * cAr - tAi * cAi;
    float nAi = tAr * cAi + tAi * cAr;
    float nPr = fmaf(tAr, cPr, fmaf(-tAi, cPi, tPr));
    float nPi = fmaf(tAr, cPi, fmaf( tAi, cPr, tPi));
    float nQr = fmaf(tAr, cQr, fmaf(-tAi, cQi, tQr));
    float nQi = fmaf(tAr, cQi, fmaf( tAi, cQr, tQi));
    cAr = nAr; cAi = nAi; cPr = nPr; cPi = nPi; cQr = nQr; cQi = nQi;
  }

  if (wv == 0) {
    float* ag = p.AGG + (size_t)g * 384 + lane;
    RSS(ag +   0, cAr); RSS(ag +  64, cAi);
    RSS(ag + 128, cPr); RSS(ag + 192, cPi);
    RSS(ag + 256, cQr); RSS(ag + 320, cQi);
  }

  gbar(&p.bar[0]);   // =============== grid barrier 1 =====================

  // ======== between barriers: block 0 = sigma; blocks 8..15 = batch scans
  if (g == 0) {
    // ---- spectral norm of W: G=WW^T (bf16 MFMA), 8 normalized squarings,
    // dominant column, fp32 Rayleigh. G^2^k stays symmetric, so B-fragments
    // read as rows (ds_read_b128) instead of strided columns.
    unsigned short* Ma = (unsigned short*)smem;          // 64*72 ushorts
    unsigned short* Mb = Ma + 64 * MP;
    float* red = (float*)(smem + 18432);
    float* vsh = red + 4;
    int*   jsh = (int*)(vsh + 64);

    floatx4 f0[4] = {};
    const int arow = 16 * wv + l15;
    for (int s = 0; s < 4; ++s) {
      const int kb = 32 * s + 8 * q;
      float4 a0 = *(const float4*)(p.W + arow * 128 + kb);
      float4 a1 = *(const float4*)(p.W + arow * 128 + kb + 4);
      ushortx8 ua;
      ua[0] = f2bf(a0.x); ua[1] = f2bf(a0.y); ua[2] = f2bf(a0.z); ua[3] = f2bf(a0.w);
      ua[4] = f2bf(a1.x); ua[5] = f2bf(a1.y); ua[6] = f2bf(a1.z); ua[7] = f2bf(a1.w);
      bf16x8 av = __builtin_bit_cast(bf16x8, ua);
      for (int tn = 0; tn < 4; ++tn) {
        const int brow = 16 * tn + l15;          // B[k][n] = W[n][k]
        float4 b0 = *(const float4*)(p.W + brow * 128 + kb);
        float4 b1 = *(const float4*)(p.W + brow * 128 + kb + 4);
        ushortx8 ub;
        ub[0] = f2bf(b0.x); ub[1] = f2bf(b0.y); ub[2] = f2bf(b0.z); ub[3] = f2bf(b0.w);
        ub[4] = f2bf(b1.x); ub[5] = f2bf(b1.y); ub[6] = f2bf(b1.z); ub[7] = f2bf(b1.w);
        bf16x8 bv = __builtin_bit_cast(bf16x8, ub);
        f0[tn] = __builtin_amdgcn_mfma_f32_16x16x32_bf16(av, bv, f0[tn], 0, 0, 0);
      }
    }
    float mx = 0.f;
    for (int tn = 0; tn < 4; ++tn)
      for (int r = 0; r < 4; ++r) mx = fmaxf(mx, fabsf(f0[tn][r]));
    for (int off = 32; off; off >>= 1) mx = fmaxf(mx, __shfl_xor(mx, off));
    if (lane == 0) red[wv] = mx;
    __syncthreads();
    {
      float gm  = fmaxf(fmaxf(red[0], red[1]), fmaxf(red[2], red[3]));
      float inv = 1.f / gm;
      for (int tn = 0; tn < 4; ++tn)
        for (int r = 0; r < 4; ++r)
          Ma[(16 * wv + 4 * q + r) * MP + 16 * tn + l15] = f2bf(f0[tn][r] * inv);
    }
    __syncthreads();

    unsigned short* srcm = Ma;
    unsigned short* dstm = Mb;
    for (int it = 0; it < 8; ++it) {
      floatx4 f[4] = {};
      for (int s = 0; s < 2; ++s) {
        const int kb = 32 * s + 8 * q;
        bf16x8 av = __builtin_bit_cast(bf16x8, *(const uint4*)(srcm + (16 * wv + l15) * MP + kb));
        for (int tn = 0; tn < 4; ++tn) {
          // symmetric: B[k][n] = M[k][n] = M[n][k] -> row read
          bf16x8 bv = __builtin_bit_cast(bf16x8, *(const uint4*)(srcm + (16 * tn + l15) * MP + kb));
          f[tn] = __builtin_amdgcn_mfma_f32_16x16x32_bf16(av, bv, f[tn], 0, 0, 0);
        }
      }
      float m2 = 0.f;
      for (int tn = 0; tn < 4; ++tn)
        for (int r = 0; r < 4; ++r) m2 = fmaxf(m2, fabsf(f[tn][r]));
      for (int off = 32; off; off >>= 1) m2 = fmaxf(m2, __shfl_xor(m2, off));
      if (lane == 0) red[wv] = m2;
      __syncthreads();
      {
        float gm2  = fmaxf(fmaxf(red[0], red[1]), fmaxf(red[2], red[3]));
        float inv2 = 1.f / gm2;
        for (int tn = 0; tn < 4; ++tn)
          for (int r = 0; r < 4; ++r)
            dstm[(16 * wv + 4 * q + r) * MP + 16 * tn + l15] = f2bf(f[tn][r] * inv2);
      }
      __syncthreads();
      unsigned short* t2 = srcm; srcm = dstm; dstm = t2;
    }

    if (tid == 0) {
      int jb = 0; float best = -1.f;
      for (int j = 0; j < 64; ++j) {
        float dv = bf2f(srcm[j * MP + j]);
        if (dv > best) { best = dv; jb = j; }
      }
      *jsh = jb;
    }
    __syncthreads();
    if (tid < 64) vsh[tid] = bf2f(srcm[tid * MP + *jsh]);
    __syncthreads();

    if (wv == 0) {
      float wa = 0.f, wb2 = 0.f;
      for (int i = 0; i < 64; ++i) {
        float vi = vsh[i];
        wa  = fmaf(p.W[i * 128 + lane], vi, wa);
        wb2 = fmaf(p.W[i * 128 + 64 + lane], vi, wb2);
      }
      float num = wa * wa + wb2 * wb2;
      float den = vsh[lane] * vsh[lane];
      for (int off = 32; off; off >>= 1) {
        num += __shfl_xor(num, off);
        den += __shfl_xor(den, off);
      }
      if (lane == 0) RSS(p.sigv, 1.f / sqrtf(num / den));
    }
  } else if (g >= 8 && g < 8 + B_ && wv == 0) {
    // ---- per-batch serial scan over 64 chunk aggregates
    const int b2 = g - 8;
    float zPr = 0.f, zPi = 0.f, zQr = 0.f, zQi = 0.f;
    const float* ag = p.AGG + (size_t)(b2 * NCPB) * 384 + lane;
    float*       z0 = p.Z0  + (size_t)(b2 * NCPB) * 256 + lane;
    for (int c2 = 0; c2 < NCPB; ++c2) {
      RSS(z0 +   0, zPr); RSS(z0 +  64, zPi);
      RSS(z0 + 128, zQr); RSS(z0 + 192, zQi);
      float tAr = RLL(ag +   0), tAi = RLL(ag +  64);
      float tPr = RLL(ag + 128), tPi = RLL(ag + 192);
      float tQr = RLL(ag + 256), tQi = RLL(ag + 320);
      float nPr = fmaf(tAr, zPr, fmaf(-tAi, zPi, tPr));
      float nPi = fmaf(tAr, zPi, fmaf( tAi, zPr, tPi));
      float nQr = fmaf(tAr, zQr, fmaf(-tAi, zQi, tQr));
      float nQi = fmaf(tAr, zQi, fmaf( tAi, zQr, tQi));
      zPr = nPr; zPi = nPi; zQr = nQr; zQi = nQi;
      ag += 384; z0 += 256;
    }
  }

  gbar(&p.bar[1]);   // =============== grid barrier 2 =====================

  // ================= phase C: replay from registers =======================
  const float invs = RLL(p.sigv);
  const float* z0p = p.Z0 + (size_t)g * 256 + lane;
  float zinPr = RLL(z0p), zinPi = RLL(z0p + 64);
  float zinQr = RLL(z0p + 128), zinQi = RLL(z0p + 192);
  float zPr = fmaf(pAr, zinPr, fmaf(-pAi, zinPi, pPr));
  float zPi = fmaf(pAr, zinPi, fmaf( pAi, zinPr, pPi));
  float zQr = fmaf(pAr, zinQr, fmaf(-pAi, zinQi, pQr));
  float zQi = fmaf(pAr, zinQi, fmaf( pAi, zinQr, pQi));

  float* op = p.out + ((size_t)bt0w << 7) + lane;
  #pragma unroll
  for (int i = 0; i < WSTEP; ++i) {
    float ar = sar[i], ai = sai[i];
    float nPr = fmaf(ar, zPr, fmaf(-ai, zPi, v[i]));
    float nPi = fmaf(ar, zPi, ai * zPr);
    zPr = nPr; zPi = nPi;
    float nQr = fmaf(ar, zQr, fmaf(-ai, zQi, bk));
    float nQi = fmaf(ar, zQi, ai * zQr);
    zQr = nQr; zQi = nQi;
    op[0]  = fmaf(invs, zPr, zQr);   // C
    op[64] = fmaf(invs, zPi, zQi);   // S
    op += 128;
  }
}

// ---------------------------------------------------------------------------
extern "C" void kernel_launch(void* const* d_in, const int* in_sizes, int n_in,
                              void* d_out, int out_size, void* d_ws, size_t ws_size,
                              hipStream_t stream) {
  (void)in_sizes; (void)n_in; (void)out_size; (void)ws_size;
  float* fws = (float*)d_ws;

  Params p;
  p.x    = (const float*)d_in[0];
  p.dtp  = (const float*)d_in[1];
  p.am   = (const float*)d_in[2];
  p.om   = (const float*)d_in[3];
  p.tm   = (const float*)d_in[4];
  p.sr   = (const float*)d_in[5];
  p.si   = (const float*)d_in[6];
  p.traw = (const float*)d_in[7];
  p.W    = (const float*)d_in[8];
  p.bb   = (const float*)d_in[9];
  p.out  = (float*)d_out;
  p.sigv = fws;                              // [1] float
  p.bar  = (int*)(fws + 4);                  // [2] ints (barrier counters)
  p.AGG  = fws + 64;                         // [512][6][64]
  p.Z0   = p.AGG + (size_t)GRID * 384;       // [512][4][64]

  hipMemsetAsync(p.bar, 0, 2 * sizeof(int), stream);  // capture-safe
  k_fused<<<GRID, 256, 0, stream>>>(p);
}

// Round 6
// 253.896 us; speedup vs baseline: 1.8441x; 1.6551x over previous
//
#include <hip/hip_runtime.h>
#include <hip/hip_bf16.h>

#define B_    8
#define T_    8192
#define CHUNK 128         // timesteps per block
#define NCPB  64          // chunks per batch
#define GRID  512         // 2 blocks/CU * 256 CU -> co-resident by construction
#define WSTEP 32          // timesteps per wave
#define TBP   65          // transpose LDS pitch (floats)
#define MP    72          // sigma LDS pitch (ushorts); 144B rows = 16B-aligned

typedef float  floatx4  __attribute__((ext_vector_type(4)));
typedef __bf16 bf16x8   __attribute__((ext_vector_type(8)));
typedef unsigned short ushortx8 __attribute__((ext_vector_type(8)));

__device__ inline unsigned short f2bf(float f) {
  unsigned u = __float_as_uint(f);
  u = u + 0x7FFFu + ((u >> 16) & 1u);   // RNE to bf16
  return (unsigned short)(u >> 16);
}
__device__ inline float bf2f(unsigned short h) {
  return __uint_as_float(((unsigned)h) << 16);
}

#define RLL(p)   __hip_atomic_load((p), __ATOMIC_RELAXED, __HIP_MEMORY_SCOPE_AGENT)
#define RSS(p,v) __hip_atomic_store((p), (v), __ATOMIC_RELAXED, __HIP_MEMORY_SCOPE_AGENT)

// Grid barrier. Counter zeroed by hipMemsetAsync before each launch.
// CRITICAL: poll with RELAXED loads (no per-iteration cache invalidate);
// a single acquire fence after release is observed. Release side: one
// threadfence (wbl2) before the arrive-add.
__device__ inline void gbar(int* ctr) {
  __syncthreads();
  if (threadIdx.x == 0) {
    __threadfence();   // release: write back dirty lines (AGG/Z0/sigv)
    __hip_atomic_fetch_add(ctr, 1, __ATOMIC_RELAXED, __HIP_MEMORY_SCOPE_AGENT);
    while (RLL(ctr) < GRID) __builtin_amdgcn_s_sleep(8);
  }
  __syncthreads();
  __builtin_amdgcn_fence(__ATOMIC_ACQUIRE, "agent");  // one invalidate
}

// per-step coefficient math (|theta| < 1e-3 so 2-term poly is fp32-exact)
#define STEP_PREP()                                                     \
    float alpha = alpha0 * __expf(a_ + tmv);                            \
    float omega = omega0 * __expf(o_ + tmv);                            \
    float rho = __expf(-alpha * dtv);                                   \
    float th  = omega * dtv;                                            \
    float th2 = th * th;                                                \
    float st  = th * fmaf(th2, -0.16666667f, 1.f);                      \
    float ct  = fmaf(th2, -0.5f, 1.f);                                  \
    float ar  = rho * ct, ai = rho * st;

struct Params {
  const float *x, *dtp, *am, *om, *tm, *sr, *si, *traw, *bb, *W;
  float *out, *AGG, *Z0, *sigv;
  int *bar;
};

__global__ __launch_bounds__(256, 2) void k_fused(Params p) {
  __shared__ __align__(16) unsigned char smem[23552];

  const int tid  = threadIdx.x;
  const int lane = tid & 63;
  const int wv   = tid >> 6;
  const int wvu  = __builtin_amdgcn_readfirstlane(wv);
  const int l15  = lane & 15;
  const int q    = lane >> 4;
  const int g    = blockIdx.x;
  const int b    = g >> 6;
  const int c    = g & (NCPB - 1);

  // ================= phase A: u = x*W^T via hi/lo bf16 MFMA ===============
  const int bt0w = b * T_ + c * CHUNK + wvu * WSTEP;

  floatx4 acc[2][4] = {};
  #pragma unroll
  for (int s = 0; s < 4; ++s) {
    bf16x8 ah[2], al[2];
    #pragma unroll
    for (int mt = 0; mt < 2; ++mt) {
      const float* xp = p.x + ((size_t)(bt0w + 16 * mt + l15) << 7) + 32 * s + 8 * q;
      float4 x0 = *(const float4*)xp;
      float4 x1 = *(const float4*)(xp + 4);
      float xs8[8] = {x0.x, x0.y, x0.z, x0.w, x1.x, x1.y, x1.z, x1.w};
      ushortx8 uh, ul;
      #pragma unroll
      for (int j = 0; j < 8; ++j) {
        unsigned short h = f2bf(xs8[j]);
        uh[j] = h;
        ul[j] = f2bf(xs8[j] - bf2f(h));
      }
      ah[mt] = __builtin_bit_cast(bf16x8, uh);
      al[mt] = __builtin_bit_cast(bf16x8, ul);
    }
    #pragma unroll
    for (int nt = 0; nt < 4; ++nt) {
      const float* wp = p.W + (16 * nt + l15) * 128 + 32 * s + 8 * q;
      float4 w0 = *(const float4*)wp;
      float4 w1 = *(const float4*)(wp + 4);
      float ws8[8] = {w0.x, w0.y, w0.z, w0.w, w1.x, w1.y, w1.z, w1.w};
      ushortx8 vh, vl;
      #pragma unroll
      for (int j = 0; j < 8; ++j) {
        unsigned short h = f2bf(ws8[j]);
        vh[j] = h;
        vl[j] = f2bf(ws8[j] - bf2f(h));
      }
      bf16x8 bh = __builtin_bit_cast(bf16x8, vh);
      bf16x8 bl = __builtin_bit_cast(bf16x8, vl);
      #pragma unroll
      for (int mt = 0; mt < 2; ++mt) {
        acc[mt][nt] = __builtin_amdgcn_mfma_f32_16x16x32_bf16(ah[mt], bh, acc[mt][nt], 0, 0, 0);
        acc[mt][nt] = __builtin_amdgcn_mfma_f32_16x16x32_bf16(al[mt], bh, acc[mt][nt], 0, 0, 0);
        acc[mt][nt] = __builtin_amdgcn_mfma_f32_16x16x32_bf16(ah[mt], bl, acc[mt][nt], 0, 0, 0);
      }
    }
  }

  // ---- transpose u per m-tile (wave-local LDS) -> v[32] kept in VGPRs
  float v[WSTEP];
  {
    float* tb = (float*)smem + wvu * 1088;   // 4352 B per wave
    #pragma unroll
    for (int mt = 0; mt < 2; ++mt) {
      #pragma unroll
      for (int nt = 0; nt < 4; ++nt)
        #pragma unroll
        for (int r = 0; r < 4; ++r)
          tb[(4 * q + r) * TBP + 16 * nt + l15] = acc[mt][nt][r];
      #pragma unroll
      for (int i = 0; i < 16; ++i) v[16 * mt + i] = tb[i * TBP + lane];
    }
  }

  // ---- coefficients on the fly + wave-local transform (A, UP, UQ)
  const float tau    = log1pf(__expf(p.traw[0])) + 1e-3f;
  const float alpha0 = (log1pf(__expf(p.sr[lane])) + 1e-6f) * tau;
  const float omega0 = p.si[lane] * tau;
  const float bk     = p.bb[lane];

  float Ar = 1.f, Ai = 0.f, UPr = 0.f, UPi = 0.f, UQr = 0.f, UQi = 0.f;
  {
    const size_t base0 = (size_t)bt0w * 64 + lane;
    #pragma unroll
    for (int i = 0; i < WSTEP; ++i) {
      float a_  = p.am[base0 + 64 * i];
      float o_  = p.om[base0 + 64 * i];
      float tmv = p.tm[bt0w + i];
      float dtv = p.dtp[bt0w + i];
      STEP_PREP();
      float nPr = fmaf(ar, UPr, fmaf(-ai, UPi, v[i]));
      float nPi = fmaf(ar, UPi, ai * UPr);
      UPr = nPr; UPi = nPi;
      float nQr = fmaf(ar, UQr, fmaf(-ai, UQi, bk));
      float nQi = fmaf(ar, UQi, ai * UQr);
      UQr = nQr; UQi = nQi;
      float nAr = fmaf(ar, Ar, -ai * Ai);
      float nAi = fmaf(ar, Ai, ai * Ar);
      Ar = nAr; Ai = nAi;
    }
  }

  // ---- publish wave transforms, compose block aggregate + my wave prefix
  float* pub = (float*)(smem + 17408);
  pub[(wv * 6 + 0) * 64 + lane] = Ar;
  pub[(wv * 6 + 1) * 64 + lane] = Ai;
  pub[(wv * 6 + 2) * 64 + lane] = UPr;
  pub[(wv * 6 + 3) * 64 + lane] = UPi;
  pub[(wv * 6 + 4) * 64 + lane] = UQr;
  pub[(wv * 6 + 5) * 64 + lane] = UQi;
  __syncthreads();

  float cAr = 1.f, cAi = 0.f, cPr = 0.f, cPi = 0.f, cQr = 0.f, cQi = 0.f;
  float pAr = 1.f, pAi = 0.f, pPr = 0.f, pPi = 0.f, pQr = 0.f, pQi = 0.f;
  #pragma unroll
  for (int w2 = 0; w2 < 4; ++w2) {
    if (w2 == wv) { pAr = cAr; pAi = cAi; pPr = cPr; pPi = cPi; pQr = cQr; pQi = cQi; }
    float tAr = pub[(w2 * 6 + 0) * 64 + lane], tAi = pub[(w2 * 6 + 1) * 64 + lane];
    float tPr = pub[(w2 * 6 + 2) * 64 + lane], tPi = pub[(w2 * 6 + 3) * 64 + lane];
    float tQr = pub[(w2 * 6 + 4) * 64 + lane], tQi = pub[(w2 * 6 + 5) * 64 + lane];
    float nAr = tAr * cAr - tAi * cAi;
    float nAi = tAr * cAi + tAi * cAr;
    float nPr = fmaf(tAr, cPr, fmaf(-tAi, cPi, tPr));
    float nPi = fmaf(tAr, cPi, fmaf( tAi, cPr, tPi));
    float nQr = fmaf(tAr, cQr, fmaf(-tAi, cQi, tQr));
    float nQi = fmaf(tAr, cQi, fmaf( tAi, cQr, tQi));
    cAr = nAr; cAi = nAi; cPr = nPr; cPi = nPi; cQr = nQr; cQi = nQi;
  }

  if (wv == 0) {
    float* ag = p.AGG + (size_t)g * 384 + lane;
    RSS(ag +   0, cAr); RSS(ag +  64, cAi);
    RSS(ag + 128, cPr); RSS(ag + 192, cPi);
    RSS(ag + 256, cQr); RSS(ag + 320, cQi);
  }

  gbar(&p.bar[0]);   // =============== grid barrier 1 =====================

  // ======== between barriers: block 0 = sigma; blocks 8..15 = batch scans
  if (g == 0) {
    unsigned short* Ma = (unsigned short*)smem;          // 64*72 ushorts
    unsigned short* Mb = Ma + 64 * MP;
    float* red = (float*)(smem + 18432);
    float* vsh = red + 4;
    int*   jsh = (int*)(vsh + 64);

    floatx4 f0[4] = {};
    const int arow = 16 * wv + l15;
    for (int s = 0; s < 4; ++s) {
      const int kb = 32 * s + 8 * q;
      float4 a0 = *(const float4*)(p.W + arow * 128 + kb);
      float4 a1 = *(const float4*)(p.W + arow * 128 + kb + 4);
      ushortx8 ua;
      ua[0] = f2bf(a0.x); ua[1] = f2bf(a0.y); ua[2] = f2bf(a0.z); ua[3] = f2bf(a0.w);
      ua[4] = f2bf(a1.x); ua[5] = f2bf(a1.y); ua[6] = f2bf(a1.z); ua[7] = f2bf(a1.w);
      bf16x8 av = __builtin_bit_cast(bf16x8, ua);
      for (int tn = 0; tn < 4; ++tn) {
        const int brow = 16 * tn + l15;
        float4 b0 = *(const float4*)(p.W + brow * 128 + kb);
        float4 b1 = *(const float4*)(p.W + brow * 128 + kb + 4);
        ushortx8 ub;
        ub[0] = f2bf(b0.x); ub[1] = f2bf(b0.y); ub[2] = f2bf(b0.z); ub[3] = f2bf(b0.w);
        ub[4] = f2bf(b1.x); ub[5] = f2bf(b1.y); ub[6] = f2bf(b1.z); ub[7] = f2bf(b1.w);
        bf16x8 bv = __builtin_bit_cast(bf16x8, ub);
        f0[tn] = __builtin_amdgcn_mfma_f32_16x16x32_bf16(av, bv, f0[tn], 0, 0, 0);
      }
    }
    float mx = 0.f;
    for (int tn = 0; tn < 4; ++tn)
      for (int r = 0; r < 4; ++r) mx = fmaxf(mx, fabsf(f0[tn][r]));
    for (int off = 32; off; off >>= 1) mx = fmaxf(mx, __shfl_xor(mx, off));
    if (lane == 0) red[wv] = mx;
    __syncthreads();
    {
      float gm  = fmaxf(fmaxf(red[0], red[1]), fmaxf(red[2], red[3]));
      float inv = 1.f / gm;
      for (int tn = 0; tn < 4; ++tn)
        for (int r = 0; r < 4; ++r)
          Ma[(16 * wv + 4 * q + r) * MP + 16 * tn + l15] = f2bf(f0[tn][r] * inv);
    }
    __syncthreads();

    unsigned short* srcm = Ma;
    unsigned short* dstm = Mb;
    for (int it = 0; it < 8; ++it) {
      floatx4 f[4] = {};
      for (int s = 0; s < 2; ++s) {
        const int kb = 32 * s + 8 * q;
        bf16x8 av = __builtin_bit_cast(bf16x8, *(const uint4*)(srcm + (16 * wv + l15) * MP + kb));
        for (int tn = 0; tn < 4; ++tn) {
          // symmetric matrix: column read == row read (ds_read_b128)
          bf16x8 bv = __builtin_bit_cast(bf16x8, *(const uint4*)(srcm + (16 * tn + l15) * MP + kb));
          f[tn] = __builtin_amdgcn_mfma_f32_16x16x32_bf16(av, bv, f[tn], 0, 0, 0);
        }
      }
      float m2 = 0.f;
      for (int tn = 0; tn < 4; ++tn)
        for (int r = 0; r < 4; ++r) m2 = fmaxf(m2, fabsf(f[tn][r]));
      for (int off = 32; off; off >>= 1) m2 = fmaxf(m2, __shfl_xor(m2, off));
      if (lane == 0) red[wv] = m2;
      __syncthreads();
      {
        float gm2  = fmaxf(fmaxf(red[0], red[1]), fmaxf(red[2], red[3]));
        float inv2 = 1.f / gm2;
        for (int tn = 0; tn < 4; ++tn)
          for (int r = 0; r < 4; ++r)
            dstm[(16 * wv + 4 * q + r) * MP + 16 * tn + l15] = f2bf(f[tn][r] * inv2);
      }
      __syncthreads();
      unsigned short* t2 = srcm; srcm = dstm; dstm = t2;
    }

    if (tid == 0) {
      int jb = 0; float best = -1.f;
      for (int j = 0; j < 64; ++j) {
        float dv = bf2f(srcm[j * MP + j]);
        if (dv > best) { best = dv; jb = j; }
      }
      *jsh = jb;
    }
    __syncthreads();
    if (tid < 64) vsh[tid] = bf2f(srcm[tid * MP + *jsh]);
    __syncthreads();

    if (wv == 0) {
      float wa = 0.f, wb2 = 0.f;
      for (int i = 0; i < 64; ++i) {
        float vi = vsh[i];
        wa  = fmaf(p.W[i * 128 + lane], vi, wa);
        wb2 = fmaf(p.W[i * 128 + 64 + lane], vi, wb2);
      }
      float num = wa * wa + wb2 * wb2;
      float den = vsh[lane] * vsh[lane];
      for (int off = 32; off; off >>= 1) {
        num += __shfl_xor(num, off);
        den += __shfl_xor(den, off);
      }
      if (lane == 0) RSS(p.sigv, 1.f / sqrtf(num / den));
    }
  } else if (g >= 8 && g < 8 + B_ && wv == 0) {
    // ---- per-batch serial scan, prefetched in groups of 8
    const int b2 = g - 8;
    float zPr = 0.f, zPi = 0.f, zQr = 0.f, zQi = 0.f;
    const float* ag = p.AGG + (size_t)(b2 * NCPB) * 384 + lane;
    float*       z0 = p.Z0  + (size_t)(b2 * NCPB) * 256 + lane;
    float pf[8][6];
    for (int grp = 0; grp < NCPB / 8; ++grp) {
      #pragma unroll
      for (int u2 = 0; u2 < 8; ++u2) {
        const float* a2 = ag + (size_t)(grp * 8 + u2) * 384;
        pf[u2][0] = RLL(a2 +   0); pf[u2][1] = RLL(a2 +  64);
        pf[u2][2] = RLL(a2 + 128); pf[u2][3] = RLL(a2 + 192);
        pf[u2][4] = RLL(a2 + 256); pf[u2][5] = RLL(a2 + 320);
      }
      #pragma unroll
      for (int u2 = 0; u2 < 8; ++u2) {
        float* z2 = z0 + (size_t)(grp * 8 + u2) * 256;
        RSS(z2 +   0, zPr); RSS(z2 +  64, zPi);
        RSS(z2 + 128, zQr); RSS(z2 + 192, zQi);
        float tAr = pf[u2][0], tAi = pf[u2][1];
        float nPr = fmaf(tAr, zPr, fmaf(-tAi, zPi, pf[u2][2]));
        float nPi = fmaf(tAr, zPi, fmaf( tAi, zPr, pf[u2][3]));
        float nQr = fmaf(tAr, zQr, fmaf(-tAi, zQi, pf[u2][4]));
        float nQi = fmaf(tAr, zQi, fmaf( tAi, zQr, pf[u2][5]));
        zPr = nPr; zPi = nPi; zQr = nQr; zQi = nQi;
      }
    }
  }

  gbar(&p.bar[1]);   // =============== grid barrier 2 =====================

  // ================= phase C: recompute coefficients, replay ==============
  const float invs = RLL(p.sigv);
  const float* z0p = p.Z0 + (size_t)g * 256 + lane;
  float zinPr = RLL(z0p), zinPi = RLL(z0p + 64);
  float zinQr = RLL(z0p + 128), zinQi = RLL(z0p + 192);
  float zPr = fmaf(pAr, zinPr, fmaf(-pAi, zinPi, pPr));
  float zPi = fmaf(pAr, zinPi, fmaf( pAi, zinPr, pPi));
  float zQr = fmaf(pAr, zinQr, fmaf(-pAi, zinQi, pQr));
  float zQi = fmaf(pAr, zinQi, fmaf( pAi, zinQr, pQi));

  {
    const size_t base0 = (size_t)bt0w * 64 + lane;
    float* op = p.out + ((size_t)bt0w << 7) + lane;
    #pragma unroll
    for (int i = 0; i < WSTEP; ++i) {
      float a_  = p.am[base0 + 64 * i];
      float o_  = p.om[base0 + 64 * i];
      float tmv = p.tm[bt0w + i];
      float dtv = p.dtp[bt0w + i];
      STEP_PREP();
      float nPr = fmaf(ar, zPr, fmaf(-ai, zPi, v[i]));
      float nPi = fmaf(ar, zPi, ai * zPr);
      zPr = nPr; zPi = nPi;
      float nQr = fmaf(ar, zQr, fmaf(-ai, zQi, bk));
      float nQi = fmaf(ar, zQi, ai * zQr);
      zQr = nQr; zQi = nQi;
      op[(size_t)i * 128]      = fmaf(invs, zPr, zQr);   // C
      op[(size_t)i * 128 + 64] = fmaf(invs, zPi, zQi);   // S
    }
  }
}

// ---------------------------------------------------------------------------
extern "C" void kernel_launch(void* const* d_in, const int* in_sizes, int n_in,
                              void* d_out, int out_size, void* d_ws, size_t ws_size,
                              hipStream_t stream) {
  (void)in_sizes; (void)n_in; (void)out_size; (void)ws_size;
  float* fws = (float*)d_ws;

  Params p;
  p.x    = (const float*)d_in[0];
  p.dtp  = (const float*)d_in[1];
  p.am   = (const float*)d_in[2];
  p.om   = (const float*)d_in[3];
  p.tm   = (const float*)d_in[4];
  p.sr   = (const float*)d_in[5];
  p.si   = (const float*)d_in[6];
  p.traw = (const float*)d_in[7];
  p.W    = (const float*)d_in[8];
  p.bb   = (const float*)d_in[9];
  p.out  = (float*)d_out;
  p.sigv = fws;                              // [1] float
  p.bar  = (int*)(fws + 4);                  // [2] ints (barrier counters)
  p.AGG  = fws + 64;                         // [512][6][64]
  p.Z0   = p.AGG + (size_t)GRID * 384;       // [512][4][64]

  hipMemsetAsync(p.bar, 0, 2 * sizeof(int), stream);  // capture-safe
  k_fused<<<GRID, 256, 0, stream>>>(p);
}